// Round 11
// baseline (142.518 us; speedup 1.0000x reference)
//
#include <hip/hip_runtime.h>

#define Ssz 2048
#define Dd  128
#define Hh  8
#define Bb  2
#define HDp 1024

typedef unsigned short u16;
typedef unsigned int   u32;

typedef __attribute__((ext_vector_type(8))) short bf16x8;   // 8 bf16 = 4 VGPRs
typedef __attribute__((ext_vector_type(4))) float f32x4;    // C/D frag

__device__ __forceinline__ float bflo(u32 w) { return __uint_as_float(w << 16); }
__device__ __forceinline__ u16 f2bf(float f) {
    u32 x = __float_as_uint(f);
    u32 r = x + 0x7fffu + ((x >> 16) & 1u);
    return (u16)(r >> 16);
}
__device__ __forceinline__ u32 pack2(float a, float b) {
    return (u32)f2bf(a) | ((u32)f2bf(b) << 16);
}

// async global->LDS, 16B per lane; LDS dest = uniform base + lane*16 (linear)
__device__ __forceinline__ void glds16(const u16* g, u16* l)
{
    __builtin_amdgcn_global_load_lds(
        (__attribute__((address_space(1))) unsigned int*)g,
        (__attribute__((address_space(3))) unsigned int*)l,
        16, 0, 0);
}

// ---- prep: W[128][1024] f32 -> W^T[1024][128] bf16; q/k/v f32 -> bf16 ------
__global__ __launch_bounds__(256)
void prep_kernel(const float* __restrict__ Wq, const float* __restrict__ Wk,
                 const float* __restrict__ Wv, const float* __restrict__ q,
                 const float* __restrict__ k, const float* __restrict__ v,
                 u16* __restrict__ WT, u16* __restrict__ Xb)
{
    const int bi = blockIdx.x;
    const int t  = threadIdx.x;
    if (bi < 48) {                          // W transpose: 3 matrices x 16 n-tiles
        __shared__ __align__(16) u16 T[64][136];
        const int which = bi >> 4;
        const int n0 = (bi & 15) << 6;
        const float* W = (which == 0) ? Wq : (which == 1) ? Wk : Wv;
        {
            const int kr = t >> 1, half = t & 1;
            const float* src = W + (size_t)kr * HDp + n0 + half * 32;
            #pragma unroll
            for (int u = 0; u < 8; ++u) {
                float4 a = *(const float4*)(src + u * 4);
                T[half * 32 + u * 4 + 0][kr] = f2bf(a.x);
                T[half * 32 + u * 4 + 1][kr] = f2bf(a.y);
                T[half * 32 + u * 4 + 2][kr] = f2bf(a.z);
                T[half * 32 + u * 4 + 3][kr] = f2bf(a.w);
            }
        }
        __syncthreads();
        {
            const int nl = t >> 2, seg = t & 3;
            u16* dst = WT + (size_t)which * (1024 * 128) + (size_t)(n0 + nl) * 128 + seg * 32;
            #pragma unroll
            for (int u = 0; u < 4; ++u)
                *(uint4*)(dst + u * 8) = *(const uint4*)(&T[nl][seg * 32 + u * 8]);
        }
    } else {                                // X convert: 3 matrices x 32 blocks
        const int idx = bi - 48;
        const int xm  = idx >> 5;
        const float* src = (xm == 0) ? q : (xm == 1) ? k : v;
        const size_t base = (size_t)(idx & 31) * 16384 + (size_t)t * 64;
        const float* s = src + base;
        u16* d = Xb + (size_t)xm * (4096 * 128) + base;
        #pragma unroll
        for (int u = 0; u < 8; ++u) {
            float4 a = *(const float4*)(s + u * 8);
            float4 b2 = *(const float4*)(s + u * 8 + 4);
            *(uint4*)(d + u * 8) = make_uint4(pack2(a.x, a.y), pack2(a.z, a.w),
                                              pack2(b2.x, b2.y), pack2(b2.z, b2.w));
        }
    }
}

// ---- Projection: 128x128 tile, LDS-staged W^T (swizzled), bf16 X direct ----
// (round-3 verbatim — best measured configuration)
__global__ __launch_bounds__(256, 3)
void proj_kernel(const u16* __restrict__ Xb, const u16* __restrict__ WT,
                 u16* __restrict__ Qp, u16* __restrict__ Kp, u16* __restrict__ VpT)
{
    __shared__ __align__(16) u16 Wt[128 * 128];     // W^T tile, XOR-swizzled

    const int t = threadIdx.x, lane = t & 63, w = t >> 6;
    const int L15 = lane & 15, quad = lane >> 4;
    const int m0 = blockIdx.x << 7;
    const int n0 = blockIdx.y << 7;
    const int which = n0 >> 10, nc0 = n0 & 1023;
    const u16* Wg = WT + (size_t)which * (1024 * 128);
    const u16* Xg = Xb + (size_t)which * (4096 * 128);

    #pragma unroll
    for (int i = 0; i < 8; ++i) {
        const int rbase = 32 * w + 4 * i;
        const int row = rbase + (lane >> 4);
        const int cu = (lane & 15) ^ (row & 7);
        glds16(Wg + (size_t)(nc0 + row) * 128 + cu * 8, &Wt[rbase * 128]);
    }
    __syncthreads();

    const char* WtB = (const char*)Wt;
    auto ldw = [&](int rn, int ks) -> bf16x8 {
        return *(const bf16x8*)(WtB + rn * 256 + ((ks * 64 + quad * 16) ^ ((rn & 7) << 4)));
    };

    f32x4 acc[2][8] = {};
    if (which < 2) {
        #pragma unroll
        for (int ks = 0; ks < 4; ++ks) {
            bf16x8 a0 = *(const bf16x8*)(Xg + (size_t)(m0 + 32 * w + L15) * 128 + ks * 32 + quad * 8);
            bf16x8 a1 = *(const bf16x8*)(Xg + (size_t)(m0 + 32 * w + 16 + L15) * 128 + ks * 32 + quad * 8);
            #pragma unroll
            for (int nt = 0; nt < 8; ++nt) {
                bf16x8 bw = ldw(nt * 16 + L15, ks);
                acc[0][nt] = __builtin_amdgcn_mfma_f32_16x16x32_bf16(a0, bw, acc[0][nt], 0, 0, 0);
                acc[1][nt] = __builtin_amdgcn_mfma_f32_16x16x32_bf16(a1, bw, acc[1][nt], 0, 0, 0);
            }
        }
        u16* dst = which ? Kp : Qp;
        #pragma unroll
        for (int ms = 0; ms < 2; ++ms)
        #pragma unroll
        for (int nt = 0; nt < 8; ++nt) {
            const int nc = nc0 + nt * 16 + L15;
            const int hh = nc >> 7, dd = nc & 127;
            #pragma unroll
            for (int r = 0; r < 4; ++r) {
                const int m  = m0 + 32 * w + ms * 16 + quad * 4 + r;
                const int bb = m >> 11, ss = m & 2047;
                dst[((size_t)((bb * Hh + hh) * Ssz + ss)) * Dd + dd] = f2bf(acc[ms][nt][r]);
            }
        }
    } else {
        #pragma unroll
        for (int ks = 0; ks < 4; ++ks) {
            bf16x8 a0 = ldw(32 * w + L15, ks);
            bf16x8 a1 = ldw(32 * w + 16 + L15, ks);
            #pragma unroll
            for (int mt = 0; mt < 8; ++mt) {
                bf16x8 bx = *(const bf16x8*)(Xg + (size_t)(m0 + mt * 16 + L15) * 128 + ks * 32 + quad * 8);
                acc[0][mt] = __builtin_amdgcn_mfma_f32_16x16x32_bf16(a0, bx, acc[0][mt], 0, 0, 0);
                acc[1][mt] = __builtin_amdgcn_mfma_f32_16x16x32_bf16(a1, bx, acc[1][mt], 0, 0, 0);
            }
        }
        #pragma unroll
        for (int ns = 0; ns < 2; ++ns)
        #pragma unroll
        for (int r = 0; r < 4; ++r) {
            const int n  = nc0 + 32 * w + ns * 16 + quad * 4 + r;
            const int hh = n >> 7, dd = n & 127;
            #pragma unroll
            for (int mt = 0; mt < 8; ++mt) {
                const int m  = m0 + mt * 16 + L15;
                const int bb = m >> 11, ss = m & 2047;
                VpT[((size_t)((bb * Hh + hh) * Dd + dd)) * Ssz + ss] = f2bf(acc[ns][mt][r]);
            }
        }
    }
}

// ---------------- Windowed flash attention v6 ------------------------------
// Round-3 structure, ONE change (m169 lesson): V is NOT LDS-staged. PV
// B-frags load 16B-contiguous directly from d-major global VpT (L2-resident,
// 8 same-(b,h) blocks per XCD reuse it). Halves staged bytes (129->64 MB),
// halves the barrier drain, deletes V swizzle, LDS 74->42 KB.
__global__ __launch_bounds__(256, 2)
void attn_kernel(const u16* __restrict__ Qp, const u16* __restrict__ Kp,
                 const u16* __restrict__ VpT, const float* __restrict__ emb,
                 float* __restrict__ out)
{
    __shared__ __align__(16) u16 KsS[2][64 * 128];   // K chunk dbuf (XOR swz) 32KB
    __shared__ __align__(16) u16 Ps[64 * 64];        // P tile (wave-private)   8KB
    __shared__ float embs[512];                      // emb * log2(e)           2KB

    const int t  = threadIdx.x;
    const int lb = blockIdx.x;
    const int xcd = lb & 7, sidx = lb >> 3;
    const int bh = (xcd << 1) | (sidx & 1);
    const int q5 = sidx >> 1;                        // 0..31
    const int i0t = (q5 & 1) ? (31 - (q5 >> 1)) : (q5 >> 1);
    const int i0 = i0t << 6;
    const int h = bh & 7, b = bh >> 3;

    const size_t hoff = (size_t)(b * Hh + h) * Ssz * Dd;
    const u16* Qh = Qp + hoff;
    const u16* Kh = Kp + hoff;
    const u16* Vh = VpT + hoff;     // d-major: [d][s]

    embs[t]       = emb[t]       * 1.4426950408889634f;
    embs[t + 256] = emb[t + 256] * 1.4426950408889634f;

    const int lane = t & 63, w = t >> 6;
    const int L15 = lane & 15, quad = lane >> 4;
    const int swL = (L15 & 7) << 4;

    // K staging only (pre-swizzled global source, linear LDS dest)
    u32 offK[4];
    #pragma unroll
    for (int i = 0; i < 4; ++i) {
        const int rr  = 16 * w + 4 * i + (lane >> 4);
        const int csk = (lane & 15) ^ (rr & 7);
        offK[i] = (u32)rr * Dd + csk * 8;
    }
    auto STAGE = [&](int buf, int j0s) {
        const u16* kg = Kh + (size_t)j0s * Dd;
        #pragma unroll
        for (int i = 0; i < 4; ++i)
            glds16(kg + offK[i], &KsS[buf][(16 * w + 4 * i) * 128]);
    };

    const int cbeg = (i0 >= 512) ? (i0 - 512) : 0;
    const int nch  = ((i0 - cbeg) >> 6) + 1;
    STAGE(0, cbeg);                 // prologue prefetch ASAP

    // Q A-fragments straight from global (L2), resident all kernel
    bf16x8 qf[4];
    #pragma unroll
    for (int ks = 0; ks < 4; ++ks)
        qf[ks] = *(const bf16x8*)(Qh + (size_t)(i0 + 16 * w + L15) * Dd + ks * 32 + quad * 8);

    const float sc2 = 0.08838834764831845f * 1.4426950408889634f; // 1/sqrt(128)*log2e
    float m_r[4], l_p[4];
    #pragma unroll
    for (int r = 0; r < 4; ++r) { m_r[r] = -10000.f; l_p[r] = 0.f; }
    f32x4 acc_o[8] = {};

    const int ibase = i0 + 16 * w + quad * 4;
    const int prow  = 16 * w + quad * 4;
    char* psB = (char*)Ps;
    const char* psBc = psB;

    for (int kc = 0; kc < nch; ++kc) {
        const int j0 = cbeg + (kc << 6);
        __syncthreads();                       // drains prev K prefetch
        if (kc + 1 < nch) STAGE((kc + 1) & 1, j0 + 64);   // one chunk in flight

        const char* KbB = (const char*)KsS[kc & 1];

        // S = Q K^T  (16 rows x 64 cols per wave)
        f32x4 s4[4] = {};
        __builtin_amdgcn_s_setprio(1);
        #pragma unroll
        for (int ks = 0; ks < 4; ++ks) {
            #pragma unroll
            for (int n = 0; n < 4; ++n) {
                bf16x8 bk = *(const bf16x8*)(KbB + (n * 16 + L15) * 256 + ((ks * 64 + quad * 16) ^ swL));
                s4[n] = __builtin_amdgcn_mfma_f32_16x16x32_bf16(qf[ks], bk, s4[n], 0, 0, 0);
            }
        }
        __builtin_amdgcn_s_setprio(0);

        float sv[4][4], mxl[4];
        if (i0 - j0 >= 64 && i0 - j0 <= 448) {
            #pragma unroll
            for (int r = 0; r < 4; ++r) {
                const int idx0 = ibase + r - j0 - L15 - 1;
                #pragma unroll
                for (int n = 0; n < 4; ++n)
                    sv[r][n] = fmaf(s4[n][r], sc2, embs[idx0 - 16 * n]);
                mxl[r] = fmaxf(fmaxf(sv[r][0], sv[r][1]), fmaxf(sv[r][2], sv[r][3]));
            }
        } else {
            #pragma unroll
            for (int r = 0; r < 4; ++r) {
                const int d0 = ibase + r - j0 - L15;
                #pragma unroll
                for (int n = 0; n < 4; ++n) {
                    const int d = d0 - 16 * n;
                    const int idx = min(max(d - 1, 0), 511);
                    const float tv = fmaf(s4[n][r], sc2, embs[idx]);
                    sv[r][n] = (d >= 1 && d <= 511) ? tv : -1e30f;
                }
                mxl[r] = fmaxf(fmaxf(sv[r][0], sv[r][1]), fmaxf(sv[r][2], sv[r][3]));
            }
        }

        const int growp = (mxl[0] > m_r[0] + 8.f) || (mxl[1] > m_r[1] + 8.f) ||
                          (mxl[2] > m_r[2] + 8.f) || (mxl[3] > m_r[3] + 8.f);
        if (!__any(growp)) {
            #pragma unroll
            for (int r = 0; r < 4; ++r) {
                float pn[4];
                #pragma unroll
                for (int n = 0; n < 4; ++n)
                    pn[n] = __builtin_amdgcn_exp2f(sv[r][n] - m_r[r]);  // <= 2^8; masked -> 0
                l_p[r] += (pn[0] + pn[1]) + (pn[2] + pn[3]);
                const int row = prow + r, swp = (row & 7) << 4;
                #pragma unroll
                for (int n = 0; n < 4; ++n)
                    *(u16*)(psB + row * 128 + (((n << 5) + (L15 << 1)) ^ swp)) = f2bf(pn[n]);
            }
        } else {
            #pragma unroll
            for (int r = 0; r < 4; ++r) {
                float m2 = mxl[r];
                m2 = fmaxf(m2, __shfl_xor(m2, 1));
                m2 = fmaxf(m2, __shfl_xor(m2, 2));
                m2 = fmaxf(m2, __shfl_xor(m2, 4));
                m2 = fmaxf(m2, __shfl_xor(m2, 8));
                const float mnew  = fmaxf(m_r[r], m2);
                const float alpha = __builtin_amdgcn_exp2f(m_r[r] - mnew);
                m_r[r] = mnew;
                float pn[4];
                #pragma unroll
                for (int n = 0; n < 4; ++n)
                    pn[n] = __builtin_amdgcn_exp2f(sv[r][n] - mnew);    // masked -> 0
                l_p[r] = l_p[r] * alpha + ((pn[0] + pn[1]) + (pn[2] + pn[3]));
                #pragma unroll
                for (int nt = 0; nt < 8; ++nt) acc_o[nt][r] *= alpha;
                const int row = prow + r, swp = (row & 7) << 4;
                #pragma unroll
                for (int n = 0; n < 4; ++n)
                    *(u16*)(psB + row * 128 + (((n << 5) + (L15 << 1)) ^ swp)) = f2bf(pn[n]);
            }
        }

        // O += P V : B-frags DIRECT from global V^T (L2) — no staging.
        // bv0: V[j0+quad*8 .. +8)[d = nt*16+L15]; bv1: +32 cols.
        bf16x8 ap0 = *(const bf16x8*)(psBc + (16 * w + L15) * 128 + ((quad * 16) ^ swL));
        bf16x8 ap1 = *(const bf16x8*)(psBc + (16 * w + L15) * 128 + ((64 + quad * 16) ^ swL));
        const u16* vb = Vh + (size_t)L15 * Ssz + j0 + quad * 8;
        __builtin_amdgcn_s_setprio(1);
        #pragma unroll
        for (int nt = 0; nt < 8; ++nt) {
            bf16x8 bv0 = *(const bf16x8*)(vb + (size_t)(nt * 16) * Ssz);
            bf16x8 bv1 = *(const bf16x8*)(vb + (size_t)(nt * 16) * Ssz + 32);
            acc_o[nt] = __builtin_amdgcn_mfma_f32_16x16x32_bf16(ap0, bv0, acc_o[nt], 0, 0, 0);
            acc_o[nt] = __builtin_amdgcn_mfma_f32_16x16x32_bf16(ap1, bv1, acc_o[nt], 0, 0, 0);
        }
        __builtin_amdgcn_s_setprio(0);
    }

    // epilogue: reduce lane-local l across the 16 j-lanes ONCE, then divide
    #pragma unroll
    for (int r = 0; r < 4; ++r) {
        const int ig = i0 + 16 * w + quad * 4 + r;
        float* o = out + ((size_t)(b * Ssz + ig)) * HDp + h * Dd;
        if (ig == 0) {
            #pragma unroll
            for (int nt = 0; nt < 8; ++nt)
                o[nt * 16 + L15] = bflo((u32)Vh[(size_t)(nt * 16 + L15) * Ssz]);
        } else {
            float ls = l_p[r];
            ls += __shfl_xor(ls, 1);
            ls += __shfl_xor(ls, 2);
            ls += __shfl_xor(ls, 4);
            ls += __shfl_xor(ls, 8);
            const float inv = 1.0f / ls;
            #pragma unroll
            for (int nt = 0; nt < 8; ++nt)
                o[nt * 16 + L15] = acc_o[nt][r] * inv;
        }
    }
}

extern "C" void kernel_launch(void* const* d_in, const int* in_sizes, int n_in,
                              void* d_out, int out_size, void* d_ws, size_t ws_size,
                              hipStream_t stream)
{
    const float* q   = (const float*)d_in[0];
    const float* k   = (const float*)d_in[1];
    const float* v   = (const float*)d_in[2];
    const float* Wq  = (const float*)d_in[3];
    const float* Wk  = (const float*)d_in[4];
    const float* Wv  = (const float*)d_in[5];
    const float* emb = (const float*)d_in[6];
    float* out = (float*)d_out;

    const size_t per = (size_t)Bb * Hh * Ssz * Dd;   // 4.19M bf16 elements each
    u16* Qp  = (u16*)d_ws;
    u16* Kp  = Qp + per;
    u16* VpT = Kp + per;
    u16* WT  = VpT + per;                            // 3*1024*128 bf16 (0.75MB)
    u16* Xb  = WT + (size_t)3 * 1024 * 128;          // 3*4096*128 bf16 (3MB)

    prep_kernel<<<dim3(144), dim3(256), 0, stream>>>(Wq, Wk, Wv, q, k, v, WT, Xb);

    proj_kernel<<<dim3(32, 24), dim3(256), 0, stream>>>(Xb, WT, Qp, Kp, VpT);

    attn_kernel<<<dim3(512), dim3(256), 0, stream>>>(Qp, Kp, VpT, emb, out);
}

// Round 12
// 137.045 us; speedup vs baseline: 1.0399x; 1.0399x over previous
//
#include <hip/hip_runtime.h>

#define Ssz 2048
#define Dd  128
#define Hh  8
#define Bb  2
#define HDp 1024

typedef unsigned short u16;
typedef unsigned int   u32;

typedef __attribute__((ext_vector_type(8))) short bf16x8;   // 8 bf16 = 4 VGPRs
typedef __attribute__((ext_vector_type(4))) float f32x4;    // C/D frag

__device__ __forceinline__ float bflo(u32 w) { return __uint_as_float(w << 16); }
__device__ __forceinline__ u16 f2bf(float f) {
    u32 x = __float_as_uint(f);
    u32 r = x + 0x7fffu + ((x >> 16) & 1u);
    return (u16)(r >> 16);
}
__device__ __forceinline__ u32 pack2(float a, float b) {
    return (u32)f2bf(a) | ((u32)f2bf(b) << 16);
}

// async global->LDS, 16B per lane; LDS dest = uniform base + lane*16 (linear)
__device__ __forceinline__ void glds16(const u16* g, u16* l)
{
    __builtin_amdgcn_global_load_lds(
        (__attribute__((address_space(1))) unsigned int*)g,
        (__attribute__((address_space(3))) unsigned int*)l,
        16, 0, 0);
}

// ---- prep: W[128][1024] f32 -> W^T[1024][128] bf16; q/k/v f32 -> bf16 ------
__global__ __launch_bounds__(256)
void prep_kernel(const float* __restrict__ Wq, const float* __restrict__ Wk,
                 const float* __restrict__ Wv, const float* __restrict__ q,
                 const float* __restrict__ k, const float* __restrict__ v,
                 u16* __restrict__ WT, u16* __restrict__ Xb)
{
    const int bi = blockIdx.x;
    const int t  = threadIdx.x;
    if (bi < 48) {                          // W transpose: 3 matrices x 16 n-tiles
        __shared__ __align__(16) u16 T[64][136];
        const int which = bi >> 4;
        const int n0 = (bi & 15) << 6;
        const float* W = (which == 0) ? Wq : (which == 1) ? Wk : Wv;
        {
            const int kr = t >> 1, half = t & 1;
            const float* src = W + (size_t)kr * HDp + n0 + half * 32;
            #pragma unroll
            for (int u = 0; u < 8; ++u) {
                float4 a = *(const float4*)(src + u * 4);
                T[half * 32 + u * 4 + 0][kr] = f2bf(a.x);
                T[half * 32 + u * 4 + 1][kr] = f2bf(a.y);
                T[half * 32 + u * 4 + 2][kr] = f2bf(a.z);
                T[half * 32 + u * 4 + 3][kr] = f2bf(a.w);
            }
        }
        __syncthreads();
        {
            const int nl = t >> 2, seg = t & 3;
            u16* dst = WT + (size_t)which * (1024 * 128) + (size_t)(n0 + nl) * 128 + seg * 32;
            #pragma unroll
            for (int u = 0; u < 4; ++u)
                *(uint4*)(dst + u * 8) = *(const uint4*)(&T[nl][seg * 32 + u * 8]);
        }
    } else {                                // X convert: 3 matrices x 32 blocks
        const int idx = bi - 48;
        const int xm  = idx >> 5;
        const float* src = (xm == 0) ? q : (xm == 1) ? k : v;
        const size_t base = (size_t)(idx & 31) * 16384 + (size_t)t * 64;
        const float* s = src + base;
        u16* d = Xb + (size_t)xm * (4096 * 128) + base;
        #pragma unroll
        for (int u = 0; u < 8; ++u) {
            float4 a = *(const float4*)(s + u * 8);
            float4 b2 = *(const float4*)(s + u * 8 + 4);
            *(uint4*)(d + u * 8) = make_uint4(pack2(a.x, a.y), pack2(a.z, a.w),
                                              pack2(b2.x, b2.y), pack2(b2.z, b2.w));
        }
    }
}

// ---- Projection: 128x128 tile, LDS-staged W^T (swizzled), bf16 X direct ----
// (round-3 verbatim — best measured configuration)
__global__ __launch_bounds__(256, 3)
void proj_kernel(const u16* __restrict__ Xb, const u16* __restrict__ WT,
                 u16* __restrict__ Qp, u16* __restrict__ Kp, u16* __restrict__ VpT)
{
    __shared__ __align__(16) u16 Wt[128 * 128];     // W^T tile, XOR-swizzled

    const int t = threadIdx.x, lane = t & 63, w = t >> 6;
    const int L15 = lane & 15, quad = lane >> 4;
    const int m0 = blockIdx.x << 7;
    const int n0 = blockIdx.y << 7;
    const int which = n0 >> 10, nc0 = n0 & 1023;
    const u16* Wg = WT + (size_t)which * (1024 * 128);
    const u16* Xg = Xb + (size_t)which * (4096 * 128);

    #pragma unroll
    for (int i = 0; i < 8; ++i) {
        const int rbase = 32 * w + 4 * i;
        const int row = rbase + (lane >> 4);
        const int cu = (lane & 15) ^ (row & 7);
        glds16(Wg + (size_t)(nc0 + row) * 128 + cu * 8, &Wt[rbase * 128]);
    }
    __syncthreads();

    const char* WtB = (const char*)Wt;
    auto ldw = [&](int rn, int ks) -> bf16x8 {
        return *(const bf16x8*)(WtB + rn * 256 + ((ks * 64 + quad * 16) ^ ((rn & 7) << 4)));
    };

    f32x4 acc[2][8] = {};
    if (which < 2) {
        #pragma unroll
        for (int ks = 0; ks < 4; ++ks) {
            bf16x8 a0 = *(const bf16x8*)(Xg + (size_t)(m0 + 32 * w + L15) * 128 + ks * 32 + quad * 8);
            bf16x8 a1 = *(const bf16x8*)(Xg + (size_t)(m0 + 32 * w + 16 + L15) * 128 + ks * 32 + quad * 8);
            #pragma unroll
            for (int nt = 0; nt < 8; ++nt) {
                bf16x8 bw = ldw(nt * 16 + L15, ks);
                acc[0][nt] = __builtin_amdgcn_mfma_f32_16x16x32_bf16(a0, bw, acc[0][nt], 0, 0, 0);
                acc[1][nt] = __builtin_amdgcn_mfma_f32_16x16x32_bf16(a1, bw, acc[1][nt], 0, 0, 0);
            }
        }
        u16* dst = which ? Kp : Qp;
        #pragma unroll
        for (int ms = 0; ms < 2; ++ms)
        #pragma unroll
        for (int nt = 0; nt < 8; ++nt) {
            const int nc = nc0 + nt * 16 + L15;
            const int hh = nc >> 7, dd = nc & 127;
            #pragma unroll
            for (int r = 0; r < 4; ++r) {
                const int m  = m0 + 32 * w + ms * 16 + quad * 4 + r;
                const int bb = m >> 11, ss = m & 2047;
                dst[((size_t)((bb * Hh + hh) * Ssz + ss)) * Dd + dd] = f2bf(acc[ms][nt][r]);
            }
        }
    } else {
        #pragma unroll
        for (int ks = 0; ks < 4; ++ks) {
            bf16x8 a0 = ldw(32 * w + L15, ks);
            bf16x8 a1 = ldw(32 * w + 16 + L15, ks);
            #pragma unroll
            for (int mt = 0; mt < 8; ++mt) {
                bf16x8 bx = *(const bf16x8*)(Xg + (size_t)(m0 + mt * 16 + L15) * 128 + ks * 32 + quad * 8);
                acc[0][mt] = __builtin_amdgcn_mfma_f32_16x16x32_bf16(a0, bx, acc[0][mt], 0, 0, 0);
                acc[1][mt] = __builtin_amdgcn_mfma_f32_16x16x32_bf16(a1, bx, acc[1][mt], 0, 0, 0);
            }
        }
        #pragma unroll
        for (int ns = 0; ns < 2; ++ns)
        #pragma unroll
        for (int r = 0; r < 4; ++r) {
            const int n  = nc0 + 32 * w + ns * 16 + quad * 4 + r;
            const int hh = n >> 7, dd = n & 127;
            #pragma unroll
            for (int mt = 0; mt < 8; ++mt) {
                const int m  = m0 + mt * 16 + L15;
                const int bb = m >> 11, ss = m & 2047;
                VpT[((size_t)((bb * Hh + hh) * Dd + dd)) * Ssz + ss] = f2bf(acc[ns][mt][r]);
            }
        }
    }
}

// ---------------- Windowed flash attention (round-3 v3, best measured) -----
// KVBLK=64, dbuf K/V via global_load_lds, ONE barrier per chunk, zero
// cross-lane softmax steady state, defer-max, XCD-affine + heavy/light pairing.
// Round-11's no-V-staging variant REGRESSED (52.4us vs ~21.6us; MfmaUtil 5.8%,
// all pipes idle -> direct-V L2 latency on the PV critical path). Reverted.
__global__ __launch_bounds__(256, 2)
void attn_kernel(const u16* __restrict__ Qp, const u16* __restrict__ Kp,
                 const u16* __restrict__ VpT, const float* __restrict__ emb,
                 float* __restrict__ out)
{
    __shared__ __align__(16) u16 KsS[2][64 * 128];   // K chunk dbuf (XOR swz)
    __shared__ __align__(16) u16 VtS[2][128 * 64];   // V^T chunk dbuf (XOR swz)
    __shared__ __align__(16) u16 Ps[64 * 64];        // P tile (wave-private rows)
    __shared__ float embs[512];                      // emb * log2(e)

    const int t  = threadIdx.x;
    const int lb = blockIdx.x;
    const int xcd = lb & 7, sidx = lb >> 3;
    const int bh = (xcd << 1) | (sidx & 1);
    const int q5 = sidx >> 1;                        // 0..31
    const int i0t = (q5 & 1) ? (31 - (q5 >> 1)) : (q5 >> 1);
    const int i0 = i0t << 6;
    const int h = bh & 7, b = bh >> 3;

    const size_t hoff = (size_t)(b * Hh + h) * Ssz * Dd;
    const u16* Qh = Qp + hoff;
    const u16* Kh = Kp + hoff;
    const u16* Vh = VpT + hoff;     // d-major: [d][s]

    embs[t]       = emb[t]       * 1.4426950408889634f;
    embs[t + 256] = emb[t + 256] * 1.4426950408889634f;

    const int lane = t & 63, w = t >> 6;
    const int L15 = lane & 15, quad = lane >> 4;
    const int swL = (L15 & 7) << 4;

    u32 offK[4], offV[4];
    #pragma unroll
    for (int i = 0; i < 4; ++i) {
        const int rr  = 16 * w + 4 * i + (lane >> 4);
        const int csk = (lane & 15) ^ (rr & 7);
        offK[i] = (u32)rr * Dd + csk * 8;
        const int dd  = 32 * w + 8 * i + (lane >> 3);
        const int csv = (lane & 7) ^ (dd & 7);
        offV[i] = (u32)dd * Ssz + csv * 8;
    }
    auto STAGE = [&](int buf, int j0s) {
        const u16* kg = Kh + (size_t)j0s * Dd;
        const u16* vg = Vh + j0s;
        #pragma unroll
        for (int i = 0; i < 4; ++i) {
            glds16(kg + offK[i], &KsS[buf][(16 * w + 4 * i) * 128]);
            glds16(vg + offV[i], &VtS[buf][(32 * w + 8 * i) * 64]);
        }
    };

    const int cbeg = (i0 >= 512) ? (i0 - 512) : 0;
    const int nch  = ((i0 - cbeg) >> 6) + 1;
    STAGE(0, cbeg);                 // prologue prefetch ASAP

    bf16x8 qf[4];
    #pragma unroll
    for (int ks = 0; ks < 4; ++ks)
        qf[ks] = *(const bf16x8*)(Qh + (size_t)(i0 + 16 * w + L15) * Dd + ks * 32 + quad * 8);

    const float sc2 = 0.08838834764831845f * 1.4426950408889634f; // 1/sqrt(128)*log2e
    float m_r[4], l_p[4];
    #pragma unroll
    for (int r = 0; r < 4; ++r) { m_r[r] = -10000.f; l_p[r] = 0.f; }
    f32x4 acc_o[8] = {};

    const int ibase = i0 + 16 * w + quad * 4;
    const int prow  = 16 * w + quad * 4;
    char* psB = (char*)Ps;
    const char* psBc = psB;

    for (int kc = 0; kc < nch; ++kc) {
        const int j0 = cbeg + (kc << 6);
        __syncthreads();                       // drains prev prefetch (vmcnt 0)
        if (kc + 1 < nch) STAGE((kc + 1) & 1, j0 + 64);   // one chunk in flight

        const char* KbB = (const char*)KsS[kc & 1];
        const char* VbB = (const char*)VtS[kc & 1];

        f32x4 s4[4] = {};
        __builtin_amdgcn_s_setprio(1);
        #pragma unroll
        for (int ks = 0; ks < 4; ++ks) {
            #pragma unroll
            for (int n = 0; n < 4; ++n) {
                bf16x8 bk = *(const bf16x8*)(KbB + (n * 16 + L15) * 256 + ((ks * 64 + quad * 16) ^ swL));
                s4[n] = __builtin_amdgcn_mfma_f32_16x16x32_bf16(qf[ks], bk, s4[n], 0, 0, 0);
            }
        }
        __builtin_amdgcn_s_setprio(0);

        float sv[4][4], mxl[4];
        if (i0 - j0 >= 64 && i0 - j0 <= 448) {
            #pragma unroll
            for (int r = 0; r < 4; ++r) {
                const int idx0 = ibase + r - j0 - L15 - 1;
                #pragma unroll
                for (int n = 0; n < 4; ++n)
                    sv[r][n] = fmaf(s4[n][r], sc2, embs[idx0 - 16 * n]);
                mxl[r] = fmaxf(fmaxf(sv[r][0], sv[r][1]), fmaxf(sv[r][2], sv[r][3]));
            }
        } else {
            #pragma unroll
            for (int r = 0; r < 4; ++r) {
                const int d0 = ibase + r - j0 - L15;
                #pragma unroll
                for (int n = 0; n < 4; ++n) {
                    const int d = d0 - 16 * n;
                    const int idx = min(max(d - 1, 0), 511);
                    const float tv = fmaf(s4[n][r], sc2, embs[idx]);
                    sv[r][n] = (d >= 1 && d <= 511) ? tv : -1e30f;
                }
                mxl[r] = fmaxf(fmaxf(sv[r][0], sv[r][1]), fmaxf(sv[r][2], sv[r][3]));
            }
        }

        const int growp = (mxl[0] > m_r[0] + 8.f) || (mxl[1] > m_r[1] + 8.f) ||
                          (mxl[2] > m_r[2] + 8.f) || (mxl[3] > m_r[3] + 8.f);
        if (!__any(growp)) {
            #pragma unroll
            for (int r = 0; r < 4; ++r) {
                float pn[4];
                #pragma unroll
                for (int n = 0; n < 4; ++n)
                    pn[n] = __builtin_amdgcn_exp2f(sv[r][n] - m_r[r]);  // <= 2^8; masked -> 0
                l_p[r] += (pn[0] + pn[1]) + (pn[2] + pn[3]);
                const int row = prow + r, swp = (row & 7) << 4;
                #pragma unroll
                for (int n = 0; n < 4; ++n)
                    *(u16*)(psB + row * 128 + (((n << 5) + (L15 << 1)) ^ swp)) = f2bf(pn[n]);
            }
        } else {
            #pragma unroll
            for (int r = 0; r < 4; ++r) {
                float m2 = mxl[r];
                m2 = fmaxf(m2, __shfl_xor(m2, 1));
                m2 = fmaxf(m2, __shfl_xor(m2, 2));
                m2 = fmaxf(m2, __shfl_xor(m2, 4));
                m2 = fmaxf(m2, __shfl_xor(m2, 8));
                const float mnew  = fmaxf(m_r[r], m2);
                const float alpha = __builtin_amdgcn_exp2f(m_r[r] - mnew);
                m_r[r] = mnew;
                float pn[4];
                #pragma unroll
                for (int n = 0; n < 4; ++n)
                    pn[n] = __builtin_amdgcn_exp2f(sv[r][n] - mnew);    // masked -> 0
                l_p[r] = l_p[r] * alpha + ((pn[0] + pn[1]) + (pn[2] + pn[3]));
                #pragma unroll
                for (int nt = 0; nt < 8; ++nt) acc_o[nt][r] *= alpha;
                const int row = prow + r, swp = (row & 7) << 4;
                #pragma unroll
                for (int n = 0; n < 4; ++n)
                    *(u16*)(psB + row * 128 + (((n << 5) + (L15 << 1)) ^ swp)) = f2bf(pn[n]);
            }
        }

        bf16x8 ap0 = *(const bf16x8*)(psBc + (16 * w + L15) * 128 + ((quad * 16) ^ swL));
        bf16x8 ap1 = *(const bf16x8*)(psBc + (16 * w + L15) * 128 + ((64 + quad * 16) ^ swL));
        __builtin_amdgcn_s_setprio(1);
        #pragma unroll
        for (int nt = 0; nt < 8; ++nt) {
            bf16x8 bv0 = *(const bf16x8*)(VbB + (nt * 16 + L15) * 128 + ((quad * 16) ^ swL));
            bf16x8 bv1 = *(const bf16x8*)(VbB + (nt * 16 + L15) * 128 + ((64 + quad * 16) ^ swL));
            acc_o[nt] = __builtin_amdgcn_mfma_f32_16x16x32_bf16(ap0, bv0, acc_o[nt], 0, 0, 0);
            acc_o[nt] = __builtin_amdgcn_mfma_f32_16x16x32_bf16(ap1, bv1, acc_o[nt], 0, 0, 0);
        }
        __builtin_amdgcn_s_setprio(0);
    }

    #pragma unroll
    for (int r = 0; r < 4; ++r) {
        const int ig = i0 + 16 * w + quad * 4 + r;
        float* o = out + ((size_t)(b * Ssz + ig)) * HDp + h * Dd;
        if (ig == 0) {
            #pragma unroll
            for (int nt = 0; nt < 8; ++nt)
                o[nt * 16 + L15] = bflo((u32)Vh[(size_t)(nt * 16 + L15) * Ssz]);
        } else {
            float ls = l_p[r];
            ls += __shfl_xor(ls, 1);
            ls += __shfl_xor(ls, 2);
            ls += __shfl_xor(ls, 4);
            ls += __shfl_xor(ls, 8);
            const float inv = 1.0f / ls;
            #pragma unroll
            for (int nt = 0; nt < 8; ++nt)
                o[nt * 16 + L15] = acc_o[nt][r] * inv;
        }
    }
}

extern "C" void kernel_launch(void* const* d_in, const int* in_sizes, int n_in,
                              void* d_out, int out_size, void* d_ws, size_t ws_size,
                              hipStream_t stream)
{
    const float* q   = (const float*)d_in[0];
    const float* k   = (const float*)d_in[1];
    const float* v   = (const float*)d_in[2];
    const float* Wq  = (const float*)d_in[3];
    const float* Wk  = (const float*)d_in[4];
    const float* Wv  = (const float*)d_in[5];
    const float* emb = (const float*)d_in[6];
    float* out = (float*)d_out;

    const size_t per = (size_t)Bb * Hh * Ssz * Dd;   // 4.19M bf16 elements each
    u16* Qp  = (u16*)d_ws;
    u16* Kp  = Qp + per;
    u16* VpT = Kp + per;
    u16* WT  = VpT + per;                            // 3*1024*128 bf16 (0.75MB)
    u16* Xb  = WT + (size_t)3 * 1024 * 128;          // 3*4096*128 bf16 (3MB)

    // DIFFERENTIAL MEASUREMENT: prep and proj launched TWICE (both idempotent).
    // (total - 120.6)/2 = prep+proj cost incl. one boundary each. Decides
    // whether the ~40-49us non-attn budget is proj (attackable) or harness
    // gap floor (done). attn is the round-3 best (single launch).
    prep_kernel<<<dim3(144), dim3(256), 0, stream>>>(Wq, Wk, Wv, q, k, v, WT, Xb);
    prep_kernel<<<dim3(144), dim3(256), 0, stream>>>(Wq, Wk, Wv, q, k, v, WT, Xb);

    proj_kernel<<<dim3(32, 24), dim3(256), 0, stream>>>(Xb, WT, Qp, Kp, VpT);
    proj_kernel<<<dim3(32, 24), dim3(256), 0, stream>>>(Xb, WT, Qp, Kp, VpT);

    attn_kernel<<<dim3(512), dim3(256), 0, stream>>>(Qp, Kp, VpT, emb, out);
}

// Round 14
// 119.884 us; speedup vs baseline: 1.1888x; 1.1431x over previous
//
#include <hip/hip_runtime.h>

#define Ssz 2048
#define Dd  128
#define Hh  8
#define Bb  2
#define HDp 1024

typedef unsigned short u16;
typedef unsigned int   u32;

typedef __attribute__((ext_vector_type(8))) short bf16x8;   // 8 bf16 = 4 VGPRs
typedef __attribute__((ext_vector_type(4))) float f32x4;    // C/D frag

__device__ __forceinline__ float bflo(u32 w) { return __uint_as_float(w << 16); }
__device__ __forceinline__ u16 f2bf(float f) {
    u32 x = __float_as_uint(f);
    u32 r = x + 0x7fffu + ((x >> 16) & 1u);
    return (u16)(r >> 16);
}
__device__ __forceinline__ u32 pack2(float a, float b) {
    return (u32)f2bf(a) | ((u32)f2bf(b) << 16);
}

// async global->LDS, 16B per lane; LDS dest = uniform base + lane*16 (linear)
__device__ __forceinline__ void glds16(const u16* g, u16* l)
{
    __builtin_amdgcn_global_load_lds(
        (__attribute__((address_space(1))) unsigned int*)g,
        (__attribute__((address_space(3))) unsigned int*)l,
        16, 0, 0);
}

// ---- prep: W[128][1024] f32 -> W^T[1024][128] bf16; q/k/v f32 -> bf16 ------
__global__ __launch_bounds__(256)
void prep_kernel(const float* __restrict__ Wq, const float* __restrict__ Wk,
                 const float* __restrict__ Wv, const float* __restrict__ q,
                 const float* __restrict__ k, const float* __restrict__ v,
                 u16* __restrict__ WT, u16* __restrict__ Xb)
{
    const int bi = blockIdx.x;
    const int t  = threadIdx.x;
    if (bi < 48) {                          // W transpose: 3 matrices x 16 n-tiles
        __shared__ __align__(16) u16 T[64][136];
        const int which = bi >> 4;
        const int n0 = (bi & 15) << 6;
        const float* W = (which == 0) ? Wq : (which == 1) ? Wk : Wv;
        {
            const int kr = t >> 1, half = t & 1;
            const float* src = W + (size_t)kr * HDp + n0 + half * 32;
            #pragma unroll
            for (int u = 0; u < 8; ++u) {
                float4 a = *(const float4*)(src + u * 4);
                T[half * 32 + u * 4 + 0][kr] = f2bf(a.x);
                T[half * 32 + u * 4 + 1][kr] = f2bf(a.y);
                T[half * 32 + u * 4 + 2][kr] = f2bf(a.z);
                T[half * 32 + u * 4 + 3][kr] = f2bf(a.w);
            }
        }
        __syncthreads();
        {
            const int nl = t >> 2, seg = t & 3;
            u16* dst = WT + (size_t)which * (1024 * 128) + (size_t)(n0 + nl) * 128 + seg * 32;
            #pragma unroll
            for (int u = 0; u < 4; ++u)
                *(uint4*)(dst + u * 8) = *(const uint4*)(&T[nl][seg * 32 + u * 8]);
        }
    } else {                                // X convert: 3 matrices x 32 blocks
        const int idx = bi - 48;
        const int xm  = idx >> 5;
        const float* src = (xm == 0) ? q : (xm == 1) ? k : v;
        const size_t base = (size_t)(idx & 31) * 16384 + (size_t)t * 64;
        const float* s = src + base;
        u16* d = Xb + (size_t)xm * (4096 * 128) + base;
        #pragma unroll
        for (int u = 0; u < 8; ++u) {
            float4 a = *(const float4*)(s + u * 8);
            float4 b2 = *(const float4*)(s + u * 8 + 4);
            *(uint4*)(d + u * 8) = make_uint4(pack2(a.x, a.y), pack2(a.z, a.w),
                                              pack2(b2.x, b2.y), pack2(b2.z, b2.w));
        }
    }
}

// ---- Projection: 128x128 tile, LDS-staged W^T (swizzled), bf16 X direct ----
// (round-3 verbatim — best measured configuration)
__global__ __launch_bounds__(256, 3)
void proj_kernel(const u16* __restrict__ Xb, const u16* __restrict__ WT,
                 u16* __restrict__ Qp, u16* __restrict__ Kp, u16* __restrict__ VpT)
{
    __shared__ __align__(16) u16 Wt[128 * 128];     // W^T tile, XOR-swizzled

    const int t = threadIdx.x, lane = t & 63, w = t >> 6;
    const int L15 = lane & 15, quad = lane >> 4;
    const int m0 = blockIdx.x << 7;
    const int n0 = blockIdx.y << 7;
    const int which = n0 >> 10, nc0 = n0 & 1023;
    const u16* Wg = WT + (size_t)which * (1024 * 128);
    const u16* Xg = Xb + (size_t)which * (4096 * 128);

    #pragma unroll
    for (int i = 0; i < 8; ++i) {
        const int rbase = 32 * w + 4 * i;
        const int row = rbase + (lane >> 4);
        const int cu = (lane & 15) ^ (row & 7);
        glds16(Wg + (size_t)(nc0 + row) * 128 + cu * 8, &Wt[rbase * 128]);
    }
    __syncthreads();

    const char* WtB = (const char*)Wt;
    auto ldw = [&](int rn, int ks) -> bf16x8 {
        return *(const bf16x8*)(WtB + rn * 256 + ((ks * 64 + quad * 16) ^ ((rn & 7) << 4)));
    };

    f32x4 acc[2][8] = {};
    if (which < 2) {
        #pragma unroll
        for (int ks = 0; ks < 4; ++ks) {
            bf16x8 a0 = *(const bf16x8*)(Xg + (size_t)(m0 + 32 * w + L15) * 128 + ks * 32 + quad * 8);
            bf16x8 a1 = *(const bf16x8*)(Xg + (size_t)(m0 + 32 * w + 16 + L15) * 128 + ks * 32 + quad * 8);
            #pragma unroll
            for (int nt = 0; nt < 8; ++nt) {
                bf16x8 bw = ldw(nt * 16 + L15, ks);
                acc[0][nt] = __builtin_amdgcn_mfma_f32_16x16x32_bf16(a0, bw, acc[0][nt], 0, 0, 0);
                acc[1][nt] = __builtin_amdgcn_mfma_f32_16x16x32_bf16(a1, bw, acc[1][nt], 0, 0, 0);
            }
        }
        u16* dst = which ? Kp : Qp;
        #pragma unroll
        for (int ms = 0; ms < 2; ++ms)
        #pragma unroll
        for (int nt = 0; nt < 8; ++nt) {
            const int nc = nc0 + nt * 16 + L15;
            const int hh = nc >> 7, dd = nc & 127;
            #pragma unroll
            for (int r = 0; r < 4; ++r) {
                const int m  = m0 + 32 * w + ms * 16 + quad * 4 + r;
                const int bb = m >> 11, ss = m & 2047;
                dst[((size_t)((bb * Hh + hh) * Ssz + ss)) * Dd + dd] = f2bf(acc[ms][nt][r]);
            }
        }
    } else {
        #pragma unroll
        for (int ks = 0; ks < 4; ++ks) {
            bf16x8 a0 = ldw(32 * w + L15, ks);
            bf16x8 a1 = ldw(32 * w + 16 + L15, ks);
            #pragma unroll
            for (int mt = 0; mt < 8; ++mt) {
                bf16x8 bx = *(const bf16x8*)(Xg + (size_t)(m0 + mt * 16 + L15) * 128 + ks * 32 + quad * 8);
                acc[0][mt] = __builtin_amdgcn_mfma_f32_16x16x32_bf16(a0, bx, acc[0][mt], 0, 0, 0);
                acc[1][mt] = __builtin_amdgcn_mfma_f32_16x16x32_bf16(a1, bx, acc[1][mt], 0, 0, 0);
            }
        }
        #pragma unroll
        for (int ns = 0; ns < 2; ++ns)
        #pragma unroll
        for (int r = 0; r < 4; ++r) {
            const int n  = nc0 + 32 * w + ns * 16 + quad * 4 + r;
            const int hh = n >> 7, dd = n & 127;
            #pragma unroll
            for (int mt = 0; mt < 8; ++mt) {
                const int m  = m0 + mt * 16 + L15;
                const int bb = m >> 11, ss = m & 2047;
                VpT[((size_t)((bb * Hh + hh) * Dd + dd)) * Ssz + ss] = f2bf(acc[ns][mt][r]);
            }
        }
    }
}

// ---------------- Windowed flash attention (round-3 v3, best measured) -----
// KVBLK=64, dbuf K/V via global_load_lds, ONE barrier per chunk, zero
// cross-lane softmax steady state, defer-max, XCD-affine + heavy/light pairing.
__global__ __launch_bounds__(256, 2)
void attn_kernel(const u16* __restrict__ Qp, const u16* __restrict__ Kp,
                 const u16* __restrict__ VpT, const float* __restrict__ emb,
                 float* __restrict__ out)
{
    __shared__ __align__(16) u16 KsS[2][64 * 128];   // K chunk dbuf (XOR swz)
    __shared__ __align__(16) u16 VtS[2][128 * 64];   // V^T chunk dbuf (XOR swz)
    __shared__ __align__(16) u16 Ps[64 * 64];        // P tile (wave-private rows)
    __shared__ float embs[512];                      // emb * log2(e)

    const int t  = threadIdx.x;
    const int lb = blockIdx.x;
    const int xcd = lb & 7, sidx = lb >> 3;
    const int bh = (xcd << 1) | (sidx & 1);
    const int q5 = sidx >> 1;                        // 0..31
    const int i0t = (q5 & 1) ? (31 - (q5 >> 1)) : (q5 >> 1);
    const int i0 = i0t << 6;
    const int h = bh & 7, b = bh >> 3;

    const size_t hoff = (size_t)(b * Hh + h) * Ssz * Dd;
    const u16* Qh = Qp + hoff;
    const u16* Kh = Kp + hoff;
    const u16* Vh = VpT + hoff;     // d-major: [d][s]

    embs[t]       = emb[t]       * 1.4426950408889634f;
    embs[t + 256] = emb[t + 256] * 1.4426950408889634f;

    const int lane = t & 63, w = t >> 6;
    const int L15 = lane & 15, quad = lane >> 4;
    const int swL = (L15 & 7) << 4;

    u32 offK[4], offV[4];
    #pragma unroll
    for (int i = 0; i < 4; ++i) {
        const int rr  = 16 * w + 4 * i + (lane >> 4);
        const int csk = (lane & 15) ^ (rr & 7);
        offK[i] = (u32)rr * Dd + csk * 8;
        const int dd  = 32 * w + 8 * i + (lane >> 3);
        const int csv = (lane & 7) ^ (dd & 7);
        offV[i] = (u32)dd * Ssz + csv * 8;
    }
    auto STAGE = [&](int buf, int j0s) {
        const u16* kg = Kh + (size_t)j0s * Dd;
        const u16* vg = Vh + j0s;
        #pragma unroll
        for (int i = 0; i < 4; ++i) {
            glds16(kg + offK[i], &KsS[buf][(16 * w + 4 * i) * 128]);
            glds16(vg + offV[i], &VtS[buf][(32 * w + 8 * i) * 64]);
        }
    };

    const int cbeg = (i0 >= 512) ? (i0 - 512) : 0;
    const int nch  = ((i0 - cbeg) >> 6) + 1;
    STAGE(0, cbeg);                 // prologue prefetch ASAP

    bf16x8 qf[4];
    #pragma unroll
    for (int ks = 0; ks < 4; ++ks)
        qf[ks] = *(const bf16x8*)(Qh + (size_t)(i0 + 16 * w + L15) * Dd + ks * 32 + quad * 8);

    const float sc2 = 0.08838834764831845f * 1.4426950408889634f; // 1/sqrt(128)*log2e
    float m_r[4], l_p[4];
    #pragma unroll
    for (int r = 0; r < 4; ++r) { m_r[r] = -10000.f; l_p[r] = 0.f; }
    f32x4 acc_o[8] = {};

    const int ibase = i0 + 16 * w + quad * 4;
    const int prow  = 16 * w + quad * 4;
    char* psB = (char*)Ps;
    const char* psBc = psB;

    for (int kc = 0; kc < nch; ++kc) {
        const int j0 = cbeg + (kc << 6);
        __syncthreads();                       // drains prev prefetch (vmcnt 0)
        if (kc + 1 < nch) STAGE((kc + 1) & 1, j0 + 64);   // one chunk in flight

        const char* KbB = (const char*)KsS[kc & 1];
        const char* VbB = (const char*)VtS[kc & 1];

        f32x4 s4[4] = {};
        __builtin_amdgcn_s_setprio(1);
        #pragma unroll
        for (int ks = 0; ks < 4; ++ks) {
            #pragma unroll
            for (int n = 0; n < 4; ++n) {
                bf16x8 bk = *(const bf16x8*)(KbB + (n * 16 + L15) * 256 + ((ks * 64 + quad * 16) ^ swL));
                s4[n] = __builtin_amdgcn_mfma_f32_16x16x32_bf16(qf[ks], bk, s4[n], 0, 0, 0);
            }
        }
        __builtin_amdgcn_s_setprio(0);

        float sv[4][4], mxl[4];
        if (i0 - j0 >= 64 && i0 - j0 <= 448) {
            #pragma unroll
            for (int r = 0; r < 4; ++r) {
                const int idx0 = ibase + r - j0 - L15 - 1;
                #pragma unroll
                for (int n = 0; n < 4; ++n)
                    sv[r][n] = fmaf(s4[n][r], sc2, embs[idx0 - 16 * n]);
                mxl[r] = fmaxf(fmaxf(sv[r][0], sv[r][1]), fmaxf(sv[r][2], sv[r][3]));
            }
        } else {
            #pragma unroll
            for (int r = 0; r < 4; ++r) {
                const int d0 = ibase + r - j0 - L15;
                #pragma unroll
                for (int n = 0; n < 4; ++n) {
                    const int d = d0 - 16 * n;
                    const int idx = min(max(d - 1, 0), 511);
                    const float tv = fmaf(s4[n][r], sc2, embs[idx]);
                    sv[r][n] = (d >= 1 && d <= 511) ? tv : -1e30f;
                }
                mxl[r] = fmaxf(fmaxf(sv[r][0], sv[r][1]), fmaxf(sv[r][2], sv[r][3]));
            }
        }

        const int growp = (mxl[0] > m_r[0] + 8.f) || (mxl[1] > m_r[1] + 8.f) ||
                          (mxl[2] > m_r[2] + 8.f) || (mxl[3] > m_r[3] + 8.f);
        if (!__any(growp)) {
            #pragma unroll
            for (int r = 0; r < 4; ++r) {
                float pn[4];
                #pragma unroll
                for (int n = 0; n < 4; ++n)
                    pn[n] = __builtin_amdgcn_exp2f(sv[r][n] - m_r[r]);  // <= 2^8; masked -> 0
                l_p[r] += (pn[0] + pn[1]) + (pn[2] + pn[3]);
                const int row = prow + r, swp = (row & 7) << 4;
                #pragma unroll
                for (int n = 0; n < 4; ++n)
                    *(u16*)(psB + row * 128 + (((n << 5) + (L15 << 1)) ^ swp)) = f2bf(pn[n]);
            }
        } else {
            #pragma unroll
            for (int r = 0; r < 4; ++r) {
                float m2 = mxl[r];
                m2 = fmaxf(m2, __shfl_xor(m2, 1));
                m2 = fmaxf(m2, __shfl_xor(m2, 2));
                m2 = fmaxf(m2, __shfl_xor(m2, 4));
                m2 = fmaxf(m2, __shfl_xor(m2, 8));
                const float mnew  = fmaxf(m_r[r], m2);
                const float alpha = __builtin_amdgcn_exp2f(m_r[r] - mnew);
                m_r[r] = mnew;
                float pn[4];
                #pragma unroll
                for (int n = 0; n < 4; ++n)
                    pn[n] = __builtin_amdgcn_exp2f(sv[r][n] - mnew);    // masked -> 0
                l_p[r] = l_p[r] * alpha + ((pn[0] + pn[1]) + (pn[2] + pn[3]));
                #pragma unroll
                for (int nt = 0; nt < 8; ++nt) acc_o[nt][r] *= alpha;
                const int row = prow + r, swp = (row & 7) << 4;
                #pragma unroll
                for (int n = 0; n < 4; ++n)
                    *(u16*)(psB + row * 128 + (((n << 5) + (L15 << 1)) ^ swp)) = f2bf(pn[n]);
            }
        }

        bf16x8 ap0 = *(const bf16x8*)(psBc + (16 * w + L15) * 128 + ((quad * 16) ^ swL));
        bf16x8 ap1 = *(const bf16x8*)(psBc + (16 * w + L15) * 128 + ((64 + quad * 16) ^ swL));
        __builtin_amdgcn_s_setprio(1);
        #pragma unroll
        for (int nt = 0; nt < 8; ++nt) {
            bf16x8 bv0 = *(const bf16x8*)(VbB + (nt * 16 + L15) * 128 + ((quad * 16) ^ swL));
            bf16x8 bv1 = *(const bf16x8*)(VbB + (nt * 16 + L15) * 128 + ((64 + quad * 16) ^ swL));
            acc_o[nt] = __builtin_amdgcn_mfma_f32_16x16x32_bf16(ap0, bv0, acc_o[nt], 0, 0, 0);
            acc_o[nt] = __builtin_amdgcn_mfma_f32_16x16x32_bf16(ap1, bv1, acc_o[nt], 0, 0, 0);
        }
        __builtin_amdgcn_s_setprio(0);
    }

    #pragma unroll
    for (int r = 0; r < 4; ++r) {
        const int ig = i0 + 16 * w + quad * 4 + r;
        float* o = out + ((size_t)(b * Ssz + ig)) * HDp + h * Dd;
        if (ig == 0) {
            #pragma unroll
            for (int nt = 0; nt < 8; ++nt)
                o[nt * 16 + L15] = bflo((u32)Vh[(size_t)(nt * 16 + L15) * Ssz]);
        } else {
            float ls = l_p[r];
            ls += __shfl_xor(ls, 1);
            ls += __shfl_xor(ls, 2);
            ls += __shfl_xor(ls, 4);
            ls += __shfl_xor(ls, 8);
            const float inv = 1.0f / ls;
            #pragma unroll
            for (int nt = 0; nt < 8; ++nt)
                o[nt * 16 + L15] = acc_o[nt][r] * inv;
        }
    }
}

extern "C" void kernel_launch(void* const* d_in, const int* in_sizes, int n_in,
                              void* d_out, int out_size, void* d_ws, size_t ws_size,
                              hipStream_t stream)
{
    const float* q   = (const float*)d_in[0];
    const float* k   = (const float*)d_in[1];
    const float* v   = (const float*)d_in[2];
    const float* Wq  = (const float*)d_in[3];
    const float* Wk  = (const float*)d_in[4];
    const float* Wv  = (const float*)d_in[5];
    const float* emb = (const float*)d_in[6];
    float* out = (float*)d_out;

    const size_t per = (size_t)Bb * Hh * Ssz * Dd;   // 4.19M bf16 elements each
    u16* Qp  = (u16*)d_ws;
    u16* Kp  = Qp + per;
    u16* VpT = Kp + per;
    u16* WT  = VpT + per;                            // 3*1024*128 bf16 (0.75MB)
    u16* Xb  = WT + (size_t)3 * 1024 * 128;          // 3*4096*128 bf16 (3MB)

    // FINAL CONFIG (round-3 best, single launches). Measured decomposition:
    // fixed harness window ~82.6us + attn ~21.6us (staging at ~6.6TB/s
    // effective, >= achievable HBM ceiling) + prep+proj ~16.4us (within
    // ~1.5x of traffic floor incl. boundaries).
    prep_kernel<<<dim3(144), dim3(256), 0, stream>>>(Wq, Wk, Wv, q, k, v, WT, Xb);

    proj_kernel<<<dim3(32, 24), dim3(256), 0, stream>>>(Xb, WT, Qp, Kp, VpT);

    attn_kernel<<<dim3(512), dim3(256), 0, stream>>>(Qp, Kp, VpT, emb, out);
}